// Round 2
// baseline (1425.360 us; speedup 1.0000x reference)
//
#include <hip/hip_runtime.h>

#define CC 32
#define HH 256
#define WW 512
#define HWSZ (HH*WW)          // 131072
#define BB 4
#define NIMG 8                // 2 sides * 4 batch, img = side*4 + b
#define EPS 1e-5f
#define MAXD 48

// conv tiling
#define TH 8
#define TW 64
#define CICH 16
#define TRN 10                // tile rows (TH+2)
#define TROW 68               // tile row stride (66 valid cols, padded for 16B align + bank spread)
#define TILE_ELEMS (CICH*TRN*TROW)   // 10880 floats = 43.5 KB
#define WLDS_ELEMS (9*CICH*CC)       // 4608 floats  = 18.4 KB

// Direct 3x3 conv, pad=1. Each block: one image, 8-row x 64-col output tile, all 32 co.
// Thread: 8 px (w) x 8 co. ci chunked by 16. Raw conv output written to yout;
// per-channel sum/sumsq accumulated via wave-reduce + atomics (for the NEXT BN).
// FUSE: input is previous raw conv output; apply relu(x*scale+shift) when staging.
template<bool FUSE>
__global__ __launch_bounds__(256) void conv3x3_k(
    const float* __restrict__ inL, const float* __restrict__ inR,
    const float* __restrict__ yin, const float* __restrict__ wgt,
    const float* __restrict__ scale, const float* __restrict__ shift,
    float* __restrict__ yout, float* __restrict__ ssum, float* __restrict__ ssq)
{
    __shared__ float tile[TILE_ELEMS];
    __shared__ float wlds[WLDS_ELEMS];

    const int tid = threadIdx.x;
    const int bx  = blockIdx.x;
    const int img = bx >> 8;            // 256 tiles per image
    const int rem = bx & 255;
    const int ty  = rem >> 3;
    const int tx  = rem & 7;
    const int y0  = ty * TH;
    const int x0  = tx * TW;
    const int side = img >> 2;

    const int pxg = tid & 7;            // 8 pixel-groups of 8 along w
    const int row = (tid >> 3) & 7;     // 8 rows
    const int cog = tid >> 6;           // 4 co-groups of 8 (== wave id)

    const float* src;
    if (FUSE) src = yin + (size_t)img * CC * HWSZ;
    else      src = (img < BB) ? (inL + (size_t)img * CC * HWSZ)
                               : (inR + (size_t)(img - BB) * CC * HWSZ);

    float acc[8][8];                    // [co][px]
    #pragma unroll
    for (int i = 0; i < 8; ++i)
        #pragma unroll
        for (int j = 0; j < 8; ++j) acc[i][j] = 0.f;

    for (int chunk = 0; chunk < CC; chunk += CICH) {
        // stage weights: wlds[((ky*3+kx)*CICH + cil)*32 + co]
        for (int e = tid; e < WLDS_ELEMS; e += 256) {
            int co  = e & 31;
            int r2  = e >> 5;           // k9*CICH + cil
            int k9  = r2 >> 4;
            int cil = r2 & 15;
            wlds[e] = wgt[(size_t)((co * CC + chunk + cil) * 9 + k9)];
        }
        // stage input tile (halo of 1, zero pad at image borders)
        for (int e = tid; e < TILE_ELEMS; e += 256) {
            int c  = e % TROW;
            int t2 = e / TROW;
            int r  = t2 % TRN;
            int ci = t2 / TRN;
            int xx = x0 + c - 1;
            int yy = y0 + r - 1;
            float v = 0.f;
            if (c < 66 && (unsigned)xx < (unsigned)WW && (unsigned)yy < (unsigned)HH) {
                v = src[(size_t)(chunk + ci) * HWSZ + (size_t)yy * WW + xx];
                if (FUSE) {
                    float s = scale[side * CC + chunk + ci];
                    float b = shift[side * CC + chunk + ci];
                    v = fmaxf(v * s + b, 0.f);
                }
            }
            tile[e] = v;
        }
        __syncthreads();

        const int colbase = pxg * 8;
        #pragma unroll 2
        for (int cil = 0; cil < CICH; ++cil) {
            #pragma unroll
            for (int ky = 0; ky < 3; ++ky) {
                const float* trow = &tile[(cil * TRN + row + ky) * TROW + colbase];
                float4 a0 = *(const float4*)(trow);
                float4 a1 = *(const float4*)(trow + 4);
                float4 a2 = *(const float4*)(trow + 8);
                float iv[12] = {a0.x,a0.y,a0.z,a0.w,a1.x,a1.y,a1.z,a1.w,a2.x,a2.y,a2.z,a2.w};
                #pragma unroll
                for (int kx = 0; kx < 3; ++kx) {
                    const float* wp = &wlds[((ky * 3 + kx) * CICH + cil) * CC + cog * 8];
                    float4 w0 = *(const float4*)(wp);
                    float4 w1 = *(const float4*)(wp + 4);
                    float wv[8] = {w0.x,w0.y,w0.z,w0.w,w1.x,w1.y,w1.z,w1.w};
                    #pragma unroll
                    for (int co = 0; co < 8; ++co)
                        #pragma unroll
                        for (int p = 0; p < 8; ++p)
                            acc[co][p] = fmaf(iv[p + kx], wv[co], acc[co][p]);
                }
            }
        }
        __syncthreads();
    }

    // store raw conv output + accumulate per-channel stats
    const size_t obase = (size_t)img * CC * HWSZ + (size_t)(y0 + row) * WW + x0 + pxg * 8;
    const int lane = tid & 63;
    #pragma unroll
    for (int co = 0; co < 8; ++co) {
        float4 s0 = make_float4(acc[co][0], acc[co][1], acc[co][2], acc[co][3]);
        float4 s1 = make_float4(acc[co][4], acc[co][5], acc[co][6], acc[co][7]);
        size_t o = obase + (size_t)(cog * 8 + co) * HWSZ;
        *(float4*)&yout[o]     = s0;
        *(float4*)&yout[o + 4] = s1;

        float s = 0.f, q = 0.f;
        #pragma unroll
        for (int p = 0; p < 8; ++p) { s += acc[co][p]; q += acc[co][p] * acc[co][p]; }
        #pragma unroll
        for (int off = 32; off > 0; off >>= 1) {
            s += __shfl_down(s, off);
            q += __shfl_down(q, off);
        }
        if (lane == 0) {
            atomicAdd(&ssum[side * CC + cog * 8 + co], s);
            atomicAdd(&ssq [side * CC + cog * 8 + co], q);
        }
    }
}

// Per (side, channel) BN finalize: scale = gamma*rsqrt(var+eps), shift = beta - mean*scale
__global__ __launch_bounds__(64) void bnfin_k(
    const float* __restrict__ ssum, const float* __restrict__ ssq,
    const float* __restrict__ gamma, const float* __restrict__ beta,
    float* __restrict__ scale, float* __restrict__ shift)
{
    int t = threadIdx.x;            // 64 = 2 sides * 32 ch
    int c = t & 31;
    const float n = (float)(BB * HWSZ);      // 524288 per side per channel
    float m  = ssum[t] / n;
    float vr = ssq[t] / n - m * m;
    float sc = gamma[c] * rsqrtf(vr + EPS);
    scale[t] = sc;
    shift[t] = beta[c] - m * sc;
}

// 1x1 conv to 1 channel with BN2+ReLU on the fly: g2[img][p] = sum_c relu(y2*s+b)*g2w[c] + g2b
__global__ __launch_bounds__(256) void g2_k(
    const float* __restrict__ y2, const float* __restrict__ scale, const float* __restrict__ shift,
    const float* __restrict__ g2w, const float* __restrict__ g2b, float* __restrict__ g2)
{
    size_t p4 = ((size_t)blockIdx.x * 256 + threadIdx.x) * 4;   // 4 pixels/thread
    int img  = (int)(p4 >> 17);                                  // /HWSZ
    int side = img >> 2;
    size_t pp = p4 & (HWSZ - 1);
    float b0 = g2b[0];
    float4 accv = make_float4(b0, b0, b0, b0);
    #pragma unroll
    for (int c = 0; c < CC; ++c) {
        float4 v = *(const float4*)&y2[((size_t)img * CC + c) * HWSZ + pp];
        float s = scale[side * CC + c];
        float b = shift[side * CC + c];
        float w = g2w[c];
        accv.x += fmaxf(v.x * s + b, 0.f) * w;
        accv.y += fmaxf(v.y * s + b, 0.f) * w;
        accv.z += fmaxf(v.z * s + b, 0.f) * w;
        accv.w += fmaxf(v.w * s + b, 0.f) * w;
    }
    *(float4*)&g2[p4] = accv;
}

// Weight volume (both directions) + final residual blend. One block per (b, h) row.
__global__ __launch_bounds__(256) void final_k(
    const float* __restrict__ y2, const float* __restrict__ scale, const float* __restrict__ shift,
    const float* __restrict__ g2, const float* __restrict__ left, const float* __restrict__ right,
    float* __restrict__ out)
{
    __shared__ float Lr[WW];
    __shared__ float Rr[WW];
    const int b = blockIdx.x >> 8;
    const int h = blockIdx.x & 255;
    const int tid = threadIdx.x;

    const size_t rowoff = (size_t)h * WW;
    Lr[tid]       = g2[(size_t)b * HWSZ + rowoff + tid];
    Lr[tid + 256] = g2[(size_t)b * HWSZ + rowoff + tid + 256];
    Rr[tid]       = g2[(size_t)(BB + b) * HWSZ + rowoff + tid];
    Rr[tid + 256] = g2[(size_t)(BB + b) * HWSZ + rowoff + tid + 256];
    __syncthreads();

    const size_t OUT_R = (size_t)BB * CC * HWSZ;   // right-output offset in d_out

    for (int w = tid; w < WW; w += 256) {
        float Lv = Lr[w], Rv = Rr[w];
        float vL = 1e30f, vR = 1e30f;
        int lo = (w - MAXD < 0) ? 0 : (w - MAXD);
        int hi = (w + MAXD - 1 > WW - 1) ? (WW - 1) : (w + MAXD - 1);
        for (int idx = lo; idx <= hi; ++idx) {
            vL = fminf(vL, fabsf(Rr[idx] - Lv));
            vR = fminf(vR, fabsf(Lr[idx] - Rv));
        }
        float wL = 1.f / (1.f + __expf(vL));   // == 1 - sigmoid(vL)
        float wR = 1.f / (1.f + __expf(vR));

        const size_t pix = rowoff + w;
        #pragma unroll 4
        for (int c = 0; c < CC; ++c) {
            size_t ioff = ((size_t)b * CC + c) * HWSZ + pix;         // index within one side
            float zL = fmaxf(y2[((size_t)b * CC + c) * HWSZ + pix]        * scale[c]      + shift[c],      0.f);
            float zR = fmaxf(y2[((size_t)(BB + b) * CC + c) * HWSZ + pix] * scale[CC + c] + shift[CC + c], 0.f);
            out[ioff]         = zL * wL + left[ioff];
            out[OUT_R + ioff] = zR * wR + right[ioff];
        }
    }
}

extern "C" void kernel_launch(void* const* d_in, const int* in_sizes, int n_in,
                              void* d_out, int out_size, void* d_ws, size_t ws_size,
                              hipStream_t stream)
{
    const float* left  = (const float*)d_in[0];
    const float* right = (const float*)d_in[1];
    const float* w1    = (const float*)d_in[2];
    const float* bn1g  = (const float*)d_in[3];
    const float* bn1b  = (const float*)d_in[4];
    const float* w2    = (const float*)d_in[5];
    const float* bn2g  = (const float*)d_in[6];
    const float* bn2b  = (const float*)d_in[7];
    const float* g2w   = (const float*)d_in[8];
    const float* g2b   = (const float*)d_in[9];
    float* out = (float*)d_out;
    float* ws  = (float*)d_ws;

    const size_t YSZ = (size_t)NIMG * CC * HWSZ;   // 33,554,432 floats
    float* y1    = ws;
    float* y2    = ws + YSZ;
    float* stats = ws + 2 * YSZ;                   // 512 floats
    float* g2buf = ws;                             // reuse y1 after conv2

    float* sum1 = stats;       float* sq1 = stats + 64;
    float* sum2 = stats + 128; float* sq2 = stats + 192;
    float* sc1  = stats + 256; float* sh1 = stats + 320;
    float* sc2  = stats + 384; float* sh2 = stats + 448;

    hipMemsetAsync(stats, 0, 512 * sizeof(float), stream);

    conv3x3_k<false><<<2048, 256, 0, stream>>>(left, right, nullptr, w1,
                                               nullptr, nullptr, y1, sum1, sq1);
    bnfin_k<<<1, 64, 0, stream>>>(sum1, sq1, bn1g, bn1b, sc1, sh1);
    conv3x3_k<true><<<2048, 256, 0, stream>>>(nullptr, nullptr, y1, w2,
                                              sc1, sh1, y2, sum2, sq2);
    bnfin_k<<<1, 64, 0, stream>>>(sum2, sq2, bn2g, bn2b, sc2, sh2);
    g2_k<<<1024, 256, 0, stream>>>(y2, sc2, sh2, g2w, g2b, g2buf);
    final_k<<<1024, 256, 0, stream>>>(y2, sc2, sh2, g2buf, left, right, out);
}

// Round 4
// 512.512 us; speedup vs baseline: 2.7811x; 2.7811x over previous
//
#include <hip/hip_runtime.h>

#define CC 32
#define HH 256
#define WW 512
#define HWSZ (HH*WW)          // 131072
#define BB 4
#define NIMG 8                // 2 sides * 4 batch, img = side*4 + b
#define EPS 1e-5f
#define MAXD 48

typedef __attribute__((ext_vector_type(8))) short short8;
typedef __attribute__((ext_vector_type(16))) float f32x16;

// LDS geometry for the MFMA conv
#define ACT_R 10              // 8 output rows + 2 halo
#define ACT_C 66              // 64 output cols + 2 halo
#define ACT_BLKS (4*ACT_R*ACT_C)   // 2640 16B blocks (4 ci-octets)
#define WL_BLKS (9*2*2*32)         // 1152 16B blocks
#define ACT_BYTES (ACT_BLKS*16)    // 42240
#define WL_BYTES (WL_BLKS*16)      // 18432
#define SM_BYTES (ACT_BYTES + WL_BYTES)   // 60672

__device__ inline unsigned short f2bf(float f) {
  unsigned int b = __builtin_bit_cast(unsigned int, f);
  b += 0x7FFFu + ((b >> 16) & 1u);        // round-to-nearest-even
  return (unsigned short)(b >> 16);
}

// Implicit-GEMM 3x3 conv, pad=1, via v_mfma_f32_32x32x16_bf16.
// Block: one image, 8-row x 64-col output tile, 4 waves (2x2), each wave
// computes 32co x (4 rows x 32 cols). LDS act layout: 16B block per
// (ci-octet g, tile row r, tile col c) -> A/B frags are single ds_read_b128.
// A = W[co][ci] (M=32,K=16-slice), B = act[ci][px] (K=16,N=32 cols of one row).
// B-frags shared across ky via input-row loop. Raw fp32 output + BN stats.
template<bool FUSE>
__global__ __launch_bounds__(256, 2) void conv3x3_mfma_k(
    const float* __restrict__ inL, const float* __restrict__ inR,
    const float* __restrict__ yin, const float* __restrict__ wgt,
    const float* __restrict__ scale, const float* __restrict__ shift,
    float* __restrict__ yout, float* __restrict__ ssum, float* __restrict__ ssq)
{
  __shared__ __align__(16) char sm[SM_BYTES];
  short8* actb = (short8*)sm;
  short8* wlb  = (short8*)(sm + ACT_BYTES);

  const int tid = threadIdx.x;
  const int bx  = blockIdx.x;
  const int img = bx >> 8;            // 256 tiles per image
  const int rem = bx & 255;
  const int ty  = rem >> 3;           // 32 row-tiles
  const int tx  = rem & 7;            // 8 col-tiles
  const int y0  = ty * 8;
  const int x0  = tx * 64;
  const int side = img >> 2;

  const float* src = FUSE ? (yin + (size_t)img * CC * HWSZ)
                          : ((img < BB) ? inL + (size_t)img * CC * HWSZ
                                        : inR + (size_t)(img - BB) * CC * HWSZ);

  // ---- stage activations: fp32 -> (BN+ReLU if FUSE) -> bf16 octets ----
  for (int e = tid; e < ACT_BLKS; e += 256) {
    int c  = e % ACT_C;
    int rg = e / ACT_C;
    int r  = rg % ACT_R;
    int g  = rg / ACT_R;                // ci octet
    int xx = x0 - 1 + c;
    int yy = y0 - 1 + r;
    short8 v;
    #pragma unroll
    for (int j = 0; j < 8; ++j) v[j] = 0;
    if ((unsigned)xx < (unsigned)WW && (unsigned)yy < (unsigned)HH) {
      const float* p = src + (size_t)(g * 8) * HWSZ + (size_t)yy * WW + xx;
      #pragma unroll
      for (int j = 0; j < 8; ++j) {
        float f = p[(size_t)j * HWSZ];
        if (FUSE) {
          f = fmaf(f, scale[side * CC + g * 8 + j], shift[side * CC + g * 8 + j]);
          f = fmaxf(f, 0.f);
        }
        v[j] = (short)f2bf(f);
      }
    }
    actb[e] = v;
  }
  // ---- stage weights: block ((s*2+t)*2+g2)*32+co holds W[co][t*16+g2*8 ..+7] for shift s ----
  for (int e = tid; e < WL_BLKS; e += 256) {
    int co = e & 31;
    int gg = e >> 5;
    int g2 = gg & 1;
    int st = gg >> 1;                   // s*2 + t
    int t  = st & 1;
    int s  = st >> 1;
    int cib = t * 16 + g2 * 8;
    short8 v;
    #pragma unroll
    for (int j = 0; j < 8; ++j)
      v[j] = (short)f2bf(wgt[(size_t)(co * CC + cib + j) * 9 + s]);
    wlb[e] = v;
  }
  __syncthreads();

  const int l   = tid & 63;
  const int wid = tid >> 6;
  const int wr  = wid >> 1;             // wave row (0..1) -> rows wr*4..wr*4+3
  const int wc  = wid & 1;              // wave col -> cols wc*32..+31
  const int lh  = l >> 5;               // k-group half
  const int ln  = l & 31;

  // A-frags (weights), hoisted: 18 x ds_read_b128
  short8 afr[18];
  #pragma unroll
  for (int st = 0; st < 18; ++st)
    afr[st] = wlb[(st * 2 + lh) * 32 + ln];

  f32x16 acc[4];
  #pragma unroll
  for (int o = 0; o < 4; ++o)
    #pragma unroll
    for (int i = 0; i < 16; ++i) acc[o][i] = 0.f;

  const int cbase = wc * 32 + ln;
  #pragma unroll
  for (int irow = 0; irow < 6; ++irow) {
    const int rr = wr * 4 + irow;       // tile input row
    #pragma unroll
    for (int t = 0; t < 2; ++t) {
      #pragma unroll
      for (int kx = 0; kx < 3; ++kx) {
        short8 b = actb[((t * 2 + lh) * ACT_R + rr) * ACT_C + cbase + kx];
        #pragma unroll
        for (int ky = 0; ky < 3; ++ky) {
          const int o = irow - ky;      // output row fed by this input row
          if (o >= 0 && o <= 3) {
            acc[o] = __builtin_amdgcn_mfma_f32_32x32x16_bf16(
                       afr[(ky * 3 + kx) * 2 + t], b, acc[o], 0, 0, 0);
          }
        }
      }
    }
  }

  // ---- store raw fp32 conv output (C/D: col=ln, co=(r&3)+8*(r>>2)+4*lh) ----
  const int ox = x0 + wc * 32 + ln;
  const size_t ibase = (size_t)img * CC * HWSZ;
  #pragma unroll
  for (int o = 0; o < 4; ++o) {
    const int oy = y0 + wr * 4 + o;
    const size_t pb = ibase + (size_t)oy * WW + ox;
    #pragma unroll
    for (int r16 = 0; r16 < 16; ++r16) {
      const int co = (r16 & 3) + 8 * (r16 >> 2) + 4 * lh;
      yout[pb + (size_t)co * HWSZ] = acc[o][r16];
    }
  }

  // ---- BN stats: per-r16 reduce over rows, xor-reduce over 32-lane half ----
  float s16[16], q16[16];
  #pragma unroll
  for (int r16 = 0; r16 < 16; ++r16) {
    float s = 0.f, q = 0.f;
    #pragma unroll
    for (int o = 0; o < 4; ++o) { float v = acc[o][r16]; s += v; q += v * v; }
    #pragma unroll
    for (int off = 16; off >= 1; off >>= 1) {
      s += __shfl_xor(s, off);
      q += __shfl_xor(q, off);
    }
    s16[r16] = s; q16[r16] = q;
  }
  __syncthreads();                       // weights no longer needed; reuse region
  float* sred = (float*)(sm + ACT_BYTES);  // [4 waves][64]: 0..31 sum, 32..63 sq
  if (ln == 0) {
    #pragma unroll
    for (int r16 = 0; r16 < 16; ++r16) {
      const int co = (r16 & 3) + 8 * (r16 >> 2) + 4 * lh;
      sred[wid * 64 + co]      = s16[r16];
      sred[wid * 64 + 32 + co] = q16[r16];
    }
  }
  __syncthreads();
  if (tid < 64) {
    float v = sred[tid] + sred[64 + tid] + sred[128 + tid] + sred[192 + tid];
    if (tid < 32) atomicAdd(&ssum[side * CC + tid], v);
    else          atomicAdd(&ssq [side * CC + tid - 32], v);
  }
}

// Per (side, channel) BN finalize: scale = gamma*rsqrt(var+eps), shift = beta - mean*scale
__global__ __launch_bounds__(64) void bnfin_k(
    const float* __restrict__ ssum, const float* __restrict__ ssq,
    const float* __restrict__ gamma, const float* __restrict__ beta,
    float* __restrict__ scale, float* __restrict__ shift)
{
    int t = threadIdx.x;            // 64 = 2 sides * 32 ch
    int c = t & 31;
    const float n = (float)(BB * HWSZ);      // 524288 per side per channel
    float m  = ssum[t] / n;
    float vr = ssq[t] / n - m * m;
    float sc = gamma[c] * rsqrtf(vr + EPS);
    scale[t] = sc;
    shift[t] = beta[c] - m * sc;
}

// 1x1 conv to 1 channel with BN2+ReLU on the fly
__global__ __launch_bounds__(256) void g2_k(
    const float* __restrict__ y2, const float* __restrict__ scale, const float* __restrict__ shift,
    const float* __restrict__ g2w, const float* __restrict__ g2b, float* __restrict__ g2)
{
    size_t p4 = ((size_t)blockIdx.x * 256 + threadIdx.x) * 4;   // 4 pixels/thread
    int img  = (int)(p4 >> 17);
    int side = img >> 2;
    size_t pp = p4 & (HWSZ - 1);
    float b0 = g2b[0];
    float4 accv = make_float4(b0, b0, b0, b0);
    #pragma unroll
    for (int c = 0; c < CC; ++c) {
        float4 v = *(const float4*)&y2[((size_t)img * CC + c) * HWSZ + pp];
        float s = scale[side * CC + c];
        float b = shift[side * CC + c];
        float w = g2w[c];
        accv.x += fmaxf(v.x * s + b, 0.f) * w;
        accv.y += fmaxf(v.y * s + b, 0.f) * w;
        accv.z += fmaxf(v.z * s + b, 0.f) * w;
        accv.w += fmaxf(v.w * s + b, 0.f) * w;
    }
    *(float4*)&g2[p4] = accv;
}

// Weight volume (both directions) + final residual blend. One block per (b, h) row.
__global__ __launch_bounds__(256) void final_k(
    const float* __restrict__ y2, const float* __restrict__ scale, const float* __restrict__ shift,
    const float* __restrict__ g2, const float* __restrict__ left, const float* __restrict__ right,
    float* __restrict__ out)
{
    __shared__ float Lr[WW];
    __shared__ float Rr[WW];
    const int b = blockIdx.x >> 8;
    const int h = blockIdx.x & 255;
    const int tid = threadIdx.x;

    const size_t rowoff = (size_t)h * WW;
    Lr[tid]       = g2[(size_t)b * HWSZ + rowoff + tid];
    Lr[tid + 256] = g2[(size_t)b * HWSZ + rowoff + tid + 256];
    Rr[tid]       = g2[(size_t)(BB + b) * HWSZ + rowoff + tid];
    Rr[tid + 256] = g2[(size_t)(BB + b) * HWSZ + rowoff + tid + 256];
    __syncthreads();

    const size_t OUT_R = (size_t)BB * CC * HWSZ;

    for (int w = tid; w < WW; w += 256) {
        float Lv = Lr[w], Rv = Rr[w];
        float vL = 1e30f, vR = 1e30f;
        int lo = (w - MAXD < 0) ? 0 : (w - MAXD);
        int hi = (w + MAXD - 1 > WW - 1) ? (WW - 1) : (w + MAXD - 1);
        for (int idx = lo; idx <= hi; ++idx) {
            vL = fminf(vL, fabsf(Rr[idx] - Lv));
            vR = fminf(vR, fabsf(Lr[idx] - Rv));
        }
        float wL = 1.f / (1.f + __expf(vL));   // == 1 - sigmoid(vL)
        float wR = 1.f / (1.f + __expf(vR));

        const size_t pix = rowoff + w;
        #pragma unroll 4
        for (int c = 0; c < CC; ++c) {
            size_t ioff = ((size_t)b * CC + c) * HWSZ + pix;
            float zL = fmaxf(y2[((size_t)b * CC + c) * HWSZ + pix]        * scale[c]      + shift[c],      0.f);
            float zR = fmaxf(y2[((size_t)(BB + b) * CC + c) * HWSZ + pix] * scale[CC + c] + shift[CC + c], 0.f);
            out[ioff]         = zL * wL + left[ioff];
            out[OUT_R + ioff] = zR * wR + right[ioff];
        }
    }
}

extern "C" void kernel_launch(void* const* d_in, const int* in_sizes, int n_in,
                              void* d_out, int out_size, void* d_ws, size_t ws_size,
                              hipStream_t stream)
{
    const float* left  = (const float*)d_in[0];
    const float* right = (const float*)d_in[1];
    const float* w1    = (const float*)d_in[2];
    const float* bn1g  = (const float*)d_in[3];
    const float* bn1b  = (const float*)d_in[4];
    const float* w2    = (const float*)d_in[5];
    const float* bn2g  = (const float*)d_in[6];
    const float* bn2b  = (const float*)d_in[7];
    const float* g2w   = (const float*)d_in[8];
    const float* g2b   = (const float*)d_in[9];
    float* out = (float*)d_out;
    float* ws  = (float*)d_ws;

    const size_t YSZ = (size_t)NIMG * CC * HWSZ;   // 33,554,432 floats
    float* y1    = ws;
    float* y2    = ws + YSZ;
    float* stats = ws + 2 * YSZ;                   // 512 floats
    float* g2buf = ws;                             // reuse y1 after conv2

    float* sum1 = stats;       float* sq1 = stats + 64;
    float* sum2 = stats + 128; float* sq2 = stats + 192;
    float* sc1  = stats + 256; float* sh1 = stats + 320;
    float* sc2  = stats + 384; float* sh2 = stats + 448;

    hipMemsetAsync(stats, 0, 512 * sizeof(float), stream);

    conv3x3_mfma_k<false><<<2048, 256, 0, stream>>>(left, right, nullptr, w1,
                                                    nullptr, nullptr, y1, sum1, sq1);
    bnfin_k<<<1, 64, 0, stream>>>(sum1, sq1, bn1g, bn1b, sc1, sh1);
    conv3x3_mfma_k<true><<<2048, 256, 0, stream>>>(nullptr, nullptr, y1, w2,
                                                   sc1, sh1, y2, sum2, sq2);
    bnfin_k<<<1, 64, 0, stream>>>(sum2, sq2, bn2g, bn2b, sc2, sh2);
    g2_k<<<1024, 256, 0, stream>>>(y2, sc2, sh2, g2w, g2b, g2buf);
    final_k<<<1024, 256, 0, stream>>>(y2, sc2, sh2, g2buf, left, right, out);
}

// Round 6
// 433.669 us; speedup vs baseline: 3.2867x; 1.1818x over previous
//
#include <hip/hip_runtime.h>

#define CC 32
#define HH 256
#define WW 512
#define HWSZ (HH*WW)          // 131072
#define BB 4
#define NIMG 8                // 2 sides * 4 batch, img = side*4 + b
#define EPS 1e-5f
#define MAXD 48

// conv act tile: 8x64 outputs + halo
#define ACT_R 10
#define ACT_C 66

typedef __attribute__((ext_vector_type(8))) short short8;    // 16B = 8 bf16
typedef __attribute__((ext_vector_type(4))) short short4v;   // 8B = 4 bf16
typedef __attribute__((ext_vector_type(16))) float f32x16;

__device__ inline unsigned short f2bf(float f) {
  unsigned int b = __builtin_bit_cast(unsigned int, f);
  b += 0x7FFFu + ((b >> 16) & 1u);        // round-to-nearest-even
  return (unsigned short)(b >> 16);
}
__device__ inline float bf2f(short s) {
  unsigned int u = ((unsigned int)(unsigned short)s) << 16;
  return __builtin_bit_cast(float, u);
}

// ---- weight pre-swizzle: OIHW fp32 -> [which][((s*2+t)*2+lh)*32+ln] short8 ----
// block i holds W[co=ln][ci = t*16+lh*8 .. +7] for tap s (=ky*3+kx), bf16.
__global__ __launch_bounds__(256) void wxpose_k(
    const float* __restrict__ w1, const float* __restrict__ w2,
    short8* __restrict__ wtr)
{
  int e = blockIdx.x * 256 + threadIdx.x;
  if (e >= 2304) return;
  int which = e >= 1152;
  int i = e - which * 1152;
  const float* w = which ? w2 : w1;
  int ln = i & 31, lh = (i >> 5) & 1, t = (i >> 6) & 1, s = i >> 7;
  short8 v;
  #pragma unroll
  for (int j = 0; j < 8; ++j)
    v[j] = (short)f2bf(w[(size_t)(ln * CC + t * 16 + lh * 8 + j) * 9 + s]);
  wtr[e] = v;
}

// ---- input transpose: fp32 NCHW -> bf16 NHWC [img][y][x][c] ----
__global__ __launch_bounds__(256) void xpose_k(
    const float* __restrict__ inL, const float* __restrict__ inR,
    short8* __restrict__ xin)
{
  const int img = blockIdx.x >> 8;
  const int y   = blockIdx.x & 255;
  const int g   = threadIdx.x >> 6;      // channel octet (wave id)
  const int xl  = threadIdx.x & 63;
  const float* src = (img < BB ? inL : inR) + (size_t)(img & 3) * CC * HWSZ + (size_t)y * WW;
  short8* dst = xin + ((size_t)img * HH + y) * WW * 4;
  #pragma unroll
  for (int xc = 0; xc < 8; ++xc) {
    int x = xc * 64 + xl;
    short8 v;
    #pragma unroll
    for (int j = 0; j < 8; ++j)
      v[j] = (short)f2bf(src[(size_t)(g * 8 + j) * HWSZ + x]);
    dst[(size_t)x * 4 + g] = v;
  }
}

// ---- implicit-GEMM 3x3 conv (pad 1) on bf16 NHWC, v_mfma_f32_32x32x16_bf16 ----
// Block: one image, 8x64 output tile, 4 waves (2 row x 2 col), wave = 32co x (4r x 32c).
// Staging: wave g stages its channel-octet: dwordx4 -> (BN+ReLU if NORM) -> ds_write_b128.
// Weights read per-lane from the pre-swizzled L2-resident wtab (no LDS).
// Output: bf16 NHWC + per-(side,channel) BN statistics.
template<bool NORM>
__global__ __launch_bounds__(256, 3) void conv_k(
    const short8* __restrict__ xin, const short8* __restrict__ wtab,
    const float* __restrict__ scale, const float* __restrict__ shift,
    short8* __restrict__ yout, float* __restrict__ ssum, float* __restrict__ ssq)
{
  __shared__ short8 actb[4 * ACT_R * ACT_C];   // 42240 B
  __shared__ float sred[256];                  // cross-wave stats

  const int tid  = threadIdx.x;
  const int img  = blockIdx.x >> 8;
  const int rem  = blockIdx.x & 255;
  const int y0   = (rem >> 3) * 8;
  const int x0   = (rem & 7) * 64;
  const int side = img >> 2;
  const int wid  = tid >> 6;
  const int lane = tid & 63;

  float scg[8], shg[8];
  if (NORM) {
    #pragma unroll
    for (int j = 0; j < 8; ++j) {
      scg[j] = scale[side * CC + wid * 8 + j];
      shg[j] = shift[side * CC + wid * 8 + j];
    }
  }

  const short8* srcimg = xin + (size_t)img * HH * WW * 4;
  #pragma unroll
  for (int i = 0; i < 11; ++i) {
    int e = lane + i * 64;
    if (e < ACT_R * ACT_C) {
      int r  = e / ACT_C;
      int c  = e - r * ACT_C;
      int yy = y0 - 1 + r;
      int xx = x0 - 1 + c;
      short8 v;
      if ((unsigned)yy < (unsigned)HH && (unsigned)xx < (unsigned)WW) {
        v = srcimg[((size_t)yy * WW + xx) * 4 + wid];
        if (NORM) {
          #pragma unroll
          for (int j = 0; j < 8; ++j) {
            float f = fmaxf(fmaf(bf2f(v[j]), scg[j], shg[j]), 0.f);
            v[j] = (short)f2bf(f);
          }
        }
      } else {
        #pragma unroll
        for (int j = 0; j < 8; ++j) v[j] = 0;   // conv zero-padding (post-BN tensor)
      }
      actb[(wid * ACT_R + r) * ACT_C + c] = v;
    }
  }
  __syncthreads();

  const int wr = wid >> 1;
  const int wc = wid & 1;
  const int lh = lane >> 5;
  const int ln = lane & 31;
  const int cbase = wc * 32 + ln;

  f32x16 acc[4];
  #pragma unroll
  for (int o = 0; o < 4; ++o)
    #pragma unroll
    for (int i = 0; i < 16; ++i) acc[o][i] = 0.f;

  #pragma unroll
  for (int t = 0; t < 2; ++t) {
    short8 afr[9];
    #pragma unroll
    for (int s = 0; s < 9; ++s)
      afr[s] = wtab[((s * 2 + t) * 2 + lh) * 32 + ln];
    #pragma unroll
    for (int irow = 0; irow < 6; ++irow) {
      const int rr = wr * 4 + irow;
      #pragma unroll
      for (int kx = 0; kx < 3; ++kx) {
        short8 b = actb[((t * 2 + lh) * ACT_R + rr) * ACT_C + cbase + kx];
        #pragma unroll
        for (int ky = 0; ky < 3; ++ky) {
          const int o = irow - ky;
          if (o >= 0 && o <= 3) {
            acc[o] = __builtin_amdgcn_mfma_f32_32x32x16_bf16(
                       afr[ky * 3 + kx], b, acc[o], 0, 0, 0);
          }
        }
      }
    }
  }

  // ---- write bf16 NHWC output. C/D: col=ln, co=(r16&3)+8*(r16>>2)+4*lh ----
  const int ox = x0 + wc * 32 + ln;
  short4v* yb = (short4v*)yout;
  #pragma unroll
  for (int o = 0; o < 4; ++o) {
    const int oy = y0 + wr * 4 + o;
    const size_t pix = ((size_t)img * HH + oy) * WW + ox;
    #pragma unroll
    for (int qq = 0; qq < 4; ++qq) {        // co run = qq*8 + lh*4 .. +3
      short4v z;
      #pragma unroll
      for (int m = 0; m < 4; ++m) z[m] = (short)f2bf(acc[o][qq * 4 + m]);
      yb[pix * 8 + qq * 2 + lh] = z;
    }
  }

  // ---- BN stats (f32 accs): row-reduce, 32-lane xor-reduce, cross-wave, atomic ----
  float s16[16], q16[16];
  #pragma unroll
  for (int r16 = 0; r16 < 16; ++r16) {
    float s = 0.f, q = 0.f;
    #pragma unroll
    for (int o = 0; o < 4; ++o) { float v = acc[o][r16]; s += v; q += v * v; }
    #pragma unroll
    for (int off = 16; off >= 1; off >>= 1) {
      s += __shfl_xor(s, off);
      q += __shfl_xor(q, off);
    }
    s16[r16] = s; q16[r16] = q;
  }
  if (ln == 0) {
    #pragma unroll
    for (int r16 = 0; r16 < 16; ++r16) {
      const int co = (r16 & 3) + 8 * (r16 >> 2) + 4 * lh;
      sred[wid * 64 + co]      = s16[r16];
      sred[wid * 64 + 32 + co] = q16[r16];
    }
  }
  __syncthreads();
  if (tid < 64) {
    float v = sred[tid] + sred[64 + tid] + sred[128 + tid] + sred[192 + tid];
    if (tid < 32) atomicAdd(&ssum[side * CC + tid], v);
    else          atomicAdd(&ssq [side * CC + tid - 32], v);
  }
}

// ---- BN finalize ----
__global__ __launch_bounds__(64) void bnfin_k(
    const float* __restrict__ ssum, const float* __restrict__ ssq,
    const float* __restrict__ gamma, const float* __restrict__ beta,
    float* __restrict__ scale, float* __restrict__ shift)
{
  int t = threadIdx.x;            // 2 sides * 32 ch
  int c = t & 31;
  const float n = (float)(BB * HWSZ);
  float m  = ssum[t] / n;
  float vr = ssq[t] / n - m * m;
  float sc = gamma[c] * rsqrtf(vr + EPS);
  scale[t] = sc;
  shift[t] = beta[c] - m * sc;
}

// ---- fused: BN2+ReLU -> g2 1x1 conv -> weight volume (both dirs) -> blend ----
// One block per (b, h) row pair. z kept in LDS bf16 for both the dot and the blend.
__global__ __launch_bounds__(256, 2) void ffinal_k(
    const short8* __restrict__ y2, const float* __restrict__ scale, const float* __restrict__ shift,
    const float* __restrict__ g2w, const float* __restrict__ g2b,
    const float* __restrict__ left, const float* __restrict__ right,
    float* __restrict__ out)
{
  __shared__ short8 zb[2][WW][4];   // 65536 B: relu(bn(y2)) both sides
  __shared__ float g2r[2][WW];      // 4096 B: g2 rows

  const int b   = blockIdx.x >> 8;
  const int h   = blockIdx.x & 255;
  const int tid = threadIdx.x;

  float wreg[32];
  #pragma unroll
  for (int g = 0; g < 8; ++g) {
    float4 t4 = *(const float4*)&g2w[g * 4];
    wreg[g * 4] = t4.x; wreg[g * 4 + 1] = t4.y; wreg[g * 4 + 2] = t4.z; wreg[g * 4 + 3] = t4.w;
  }
  const float g2b0 = g2b[0];

  #pragma unroll
  for (int side = 0; side < 2; ++side) {
    float scs[32], shs[32];
    #pragma unroll
    for (int g = 0; g < 8; ++g) {
      float4 a = *(const float4*)&scale[side * CC + g * 4];
      float4 c4 = *(const float4*)&shift[side * CC + g * 4];
      scs[g * 4] = a.x; scs[g * 4 + 1] = a.y; scs[g * 4 + 2] = a.z; scs[g * 4 + 3] = a.w;
      shs[g * 4] = c4.x; shs[g * 4 + 1] = c4.y; shs[g * 4 + 2] = c4.z; shs[g * 4 + 3] = c4.w;
    }
    const int img = side * BB + b;
    #pragma unroll
    for (int it = 0; it < 2; ++it) {
      const int x = it * 256 + tid;
      const size_t pixb = (((size_t)img * HH + h) * WW + x) * 4;
      float d = g2b0;
      #pragma unroll
      for (int g = 0; g < 4; ++g) {
        short8 v = y2[pixb + g];
        short8 z;
        #pragma unroll
        for (int j = 0; j < 8; ++j) {
          float f = fmaxf(fmaf(bf2f(v[j]), scs[g * 8 + j], shs[g * 8 + j]), 0.f);
          d += f * wreg[g * 8 + j];
          z[j] = (short)f2bf(f);
        }
        zb[side][x][g] = z;
      }
      g2r[side][x] = d;
    }
  }
  __syncthreads();

  const size_t OUT_R = (size_t)BB * CC * HWSZ;
  #pragma unroll
  for (int it = 0; it < 2; ++it) {
    const int x = it * 256 + tid;
    const float Lv = g2r[0][x], Rv = g2r[1][x];
    float vL = 1e30f, vR = 1e30f;
    const int lo = (x - MAXD < 0) ? 0 : (x - MAXD);
    const int hi = (x + MAXD - 1 > WW - 1) ? (WW - 1) : (x + MAXD - 1);
    for (int idx = lo; idx <= hi; ++idx) {
      vL = fminf(vL, fabsf(g2r[1][idx] - Lv));
      vR = fminf(vR, fabsf(g2r[0][idx] - Rv));
    }
    const float wL = 1.f / (1.f + __expf(vL));
    const float wR = 1.f / (1.f + __expf(vR));

    #pragma unroll
    for (int side = 0; side < 2; ++side) {
      const float wgt = side ? wR : wL;
      const float* inp = (side ? right : left) + (size_t)b * CC * HWSZ + (size_t)h * WW + x;
      float* op = out + (side ? OUT_R : 0) + (size_t)b * CC * HWSZ + (size_t)h * WW + x;
      short8 zz[4];
      #pragma unroll
      for (int g = 0; g < 4; ++g) zz[g] = zb[side][x][g];
      #pragma unroll
      for (int g = 0; g < 4; ++g)
        #pragma unroll
        for (int j = 0; j < 8; ++j) {
          const int c = g * 8 + j;
          op[(size_t)c * HWSZ] = bf2f(zz[g][j]) * wgt + inp[(size_t)c * HWSZ];
        }
    }
  }
}

extern "C" void kernel_launch(void* const* d_in, const int* in_sizes, int n_in,
                              void* d_out, int out_size, void* d_ws, size_t ws_size,
                              hipStream_t stream)
{
  const float* left  = (const float*)d_in[0];
  const float* right = (const float*)d_in[1];
  const float* w1    = (const float*)d_in[2];
  const float* bn1g  = (const float*)d_in[3];
  const float* bn1b  = (const float*)d_in[4];
  const float* w2    = (const float*)d_in[5];
  const float* bn2g  = (const float*)d_in[6];
  const float* bn2b  = (const float*)d_in[7];
  const float* g2w   = (const float*)d_in[8];
  const float* g2b   = (const float*)d_in[9];
  float* out = (float*)d_out;

  const size_t NB = (size_t)NIMG * HH * WW * 4;   // short8 blocks per NHWC tensor
  short8* xin = (short8*)d_ws;
  short8* y1  = xin + NB;
  short8* y2  = y1 + NB;
  short8* wtr = y2 + NB;                          // 2304 blocks (w1 then w2)
  float* stats = (float*)(wtr + 2304);

  float* sum1 = stats;       float* sq1 = stats + 64;
  float* sum2 = stats + 128; float* sq2 = stats + 192;
  float* sc1  = stats + 256; float* sh1 = stats + 320;
  float* sc2  = stats + 384; float* sh2 = stats + 448;

  hipMemsetAsync(stats, 0, 512 * sizeof(float), stream);

  wxpose_k<<<9, 256, 0, stream>>>(w1, w2, wtr);
  xpose_k<<<2048, 256, 0, stream>>>(left, right, xin);
  conv_k<false><<<2048, 256, 0, stream>>>(xin, wtr, nullptr, nullptr, y1, sum1, sq1);
  bnfin_k<<<1, 64, 0, stream>>>(sum1, sq1, bn1g, bn1b, sc1, sh1);
  conv_k<true><<<2048, 256, 0, stream>>>(y1, wtr + 1152, sc1, sh1, y2, sum2, sq2);
  bnfin_k<<<1, 64, 0, stream>>>(sum2, sq2, bn2g, bn2b, sc2, sh2);
  ffinal_k<<<1024, 256, 0, stream>>>(y2, sc2, sh2, g2w, g2b, left, right, out);
}